// Round 2
// baseline (162.750 us; speedup 1.0000x reference)
//
#include <hip/hip_runtime.h>
#include <math.h>

#define HH 512
#define WW 512
#define HW (HH*WW)   // 262144

// Fused sobel+NMS tile geometry: each block computes a 64x16 gm region
// (identical per-pixel math to the previous k3) and outputs the interior
// 62x14 pixels after NMS against the LDS-resident gm halo.
#define OTW 62
#define OTH 14

__device__ __forceinline__ int refl(int i) {
  if (i < 0) return -i;
  if (i >= HH) return 2*HH - 2 - i;
  return i;
}

__device__ __forceinline__ float sumsq3(float r, float g, float b) {
  return __fadd_rn(__fadd_rn(__fmul_rn(r,r), __fmul_rn(g,g)), __fmul_rn(b,b));
}

// K1: mag = sqrt(sumsq over 3 channels), stored for k34, + global max via
// one atomicMax per block on float-as-uint bits (all values >= 0, so the
// uint ordering == float ordering). sqrtf is correctly rounded + monotone,
// so max_i sqrtf(ss_i) == sqrtf(max_i ss_i) BIT-EXACTLY -> mm unchanged
// vs the previous two-kernel reduction.
__global__ __launch_bounds__(256) void k1_mag(const float* __restrict__ img,
                                              float* __restrict__ mag,
                                              unsigned int* __restrict__ maxbits) {
  int gid = blockIdx.x * 256 + threadIdx.x;   // 0 .. 1048575 (float4 granules)
  int n  = gid >> 16;                         // 65536 float4 per image plane
  int p4 = gid & 65535;
  const float* base = img + (size_t)n * 3 * HW;
  float4 r = ((const float4*)(base        ))[p4];
  float4 g = ((const float4*)(base +   HW ))[p4];
  float4 b = ((const float4*)(base + 2*HW ))[p4];
  float4 s;
  s.x = sqrtf(sumsq3(r.x, g.x, b.x));
  s.y = sqrtf(sumsq3(r.y, g.y, b.y));
  s.z = sqrtf(sumsq3(r.z, g.z, b.z));
  s.w = sqrtf(sumsq3(r.w, g.w, b.w));
  ((float4*)mag)[gid] = s;

  float m = fmaxf(fmaxf(s.x, s.y), fmaxf(s.z, s.w));
  #pragma unroll
  for (int off = 32; off > 0; off >>= 1)
    m = fmaxf(m, __shfl_down(m, off));
  __shared__ float sm[4];
  int lane = threadIdx.x & 63, wv = threadIdx.x >> 6;
  if (lane == 0) sm[wv] = m;
  __syncthreads();
  if (threadIdx.x == 0) {
    float bm = fmaxf(fmaxf(sm[0], sm[1]), fmaxf(sm[2], sm[3]));
    atomicMax(maxbits, __float_as_uint(bm));   // nonneg floats: bit order == value order
  }
}

// K34: normalize + 5x5 Sobel + grad_mag + phase + NMS + threshold, fused.
// gm region per block: 64 cols x 16 rows at image offset (oy0-1, ox0-1);
// outputs = interior 62x14. Per-pixel math is expression-identical to the
// previous rounds (same f64 row-aggregate factorization, same f32 rounding
// points, same zero-pad NMS semantics) -> bit-stable decisions.
__global__ __launch_bounds__(256) void k34_sobel_nms(const float* __restrict__ mag,
                                                     const float* __restrict__ ssmax,
                                                     float* __restrict__ sobel_out,
                                                     float* __restrict__ edges) {
  __shared__ float magS[20 * 68];  // mag rows [oy0-3, oy0+17), cols [ox0-3, ox0+65)
  __shared__ float gmS[16 * 64];   // gm region
  int tx = threadIdx.x;            // 0..63 -> gm col
  int ty = threadIdx.y;            // 0..3
  int ox0 = blockIdx.x * OTW;      // first output col
  int oy0 = blockIdx.y * OTH;      // first output row
  int n  = blockIdx.z;
  const float* sp = mag + (size_t)n * HW;
  float mm = ssmax[0];             // == sqrtf(max ss), bit-identical to before

  int tid = ty * 64 + tx;
  for (int i = tid; i < 20 * 68; i += 256) {
    int r = i / 68, c = i - r * 68;
    int gy = refl(oy0 - 3 + r);
    int gx = refl(ox0 - 3 + c);
    magS[i] = __fdiv_rn(sp[gy * WW + gx], mm);   // bit-identical to prior rounds
  }
  __syncthreads();

  // exact f32 weights (numpy-folded), widened to f64 exactly
  const double wA0 = (double)(-2.0f/8.0f/6.0f);
  const double wA1 = (double)(-2.0f/5.0f/6.0f);
  const double wA2 = (double)(-2.0f/1.0f/6.0f);
  const double wB0 = (double)(-1.0f/5.0f/6.0f);
  const double wB1 = (double)(-1.0f/2.0f/6.0f);
  const double wB2 = (double)(-1.0f/1.0f/6.0f);

  // per-row aggregates over the thread's 8-row window (tile rows 4ty..4ty+7)
  double S[8], T[8], C[8], D0[8], D1[8];
  #pragma unroll
  for (int j = 0; j < 8; ++j) {
    const float* rowp = &magS[(4 * ty + j) * 68 + tx];
    double v0 = (double)rowp[0], v1 = (double)rowp[1], v2 = (double)rowp[2],
           v3 = (double)rowp[3], v4 = (double)rowp[4];
    S[j]  = v0 + v4;  T[j]  = v1 + v3;  C[j] = v2;
    D0[j] = v0 - v4;  D1[j] = v1 - v3;
  }

  int x = ox0 - 1 + tx;            // image col of this thread's gm column
  bool xin = (tx >= 1) && (tx <= OTW) && (x < WW);
  int prpack = 0;                  // 2 bits per dy
  #pragma unroll
  for (int dy = 0; dy < 4; ++dy) {
    int r = 4 * ty + dy;           // gm-region row, 0..15
    int y = oy0 - 1 + r;           // image row
    int j = dy;                    // window base in aggregate arrays
    double asy = wA0*(S[j]-S[j+4]) + wA1*(T[j]-T[j+4]) + wA2*(C[j]-C[j+4])
               + wB0*(S[j+1]-S[j+3]) + wB1*(T[j+1]-T[j+3]) + wB2*(C[j+1]-C[j+3]);
    double asx = wA0*(D0[j]+D0[j+4]) + wA1*(D0[j+1]+D0[j+3]) + wA2*D0[j+2]
               + wB0*(D1[j]+D1[j+4]) + wB1*(D1[j+1]+D1[j+3]) + wB2*D1[j+2];
    float fsy = (float)asy, fsx = (float)asx;
    float g = sqrtf(__fadd_rn(__fmul_rn(fsx, fsx), __fmul_rn(fsy, fsy)));
    gmS[r * 64 + tx] = g;
    float ph = atan2f(fsx, __fadd_rn(fsy, 1e-5f));
    float pf = __fdiv_rn(ph, 0.78539816339744830962f);  // f32(pi/4)
    float rr = rintf(pf);                                // half-to-even like jnp.round
    int ip = ((int)rr + 4) & 7;                          // mod 8
    prpack |= (ip & 3) << (2 * dy);                      // SEL_IDS has period 4
    // sobel store for interior pixels
    if (xin && r >= 1 && r <= OTH && y < HH) {
      int p = y * WW + x;
      sobel_out[(size_t)n * 2 * HW + p]      = fsy;  // channel 0: sobel_y
      sobel_out[(size_t)n * 2 * HW + HW + p] = fsx;  // channel 1: sobel_x
    }
  }
  __syncthreads();

  // NMS + threshold on interior pixels, neighbors from LDS (zero-pad at image border)
  if (xin) {
    const int dy0[4] = {-1, -1,  0, -1};
    const int dx0[4] = { 0, -1, -1,  1};
    const int dy1[4] = { 1,  1,  0,  1};
    const int dx1[4] = { 0,  1,  1, -1};
    #pragma unroll
    for (int dy = 0; dy < 4; ++dy) {
      int r = 4 * ty + dy;
      if (r < 1 || r > OTH) continue;      // wave-uniform branch
      int y = oy0 - 1 + r;
      if (y >= HH) continue;
      int pr = (prpack >> (2 * dy)) & 3;
      float g = gmS[r * 64 + tx];
      int yy0 = y + dy0[pr], xx0 = x + dx0[pr];
      int yy1 = y + dy1[pr], xx1 = x + dx1[pr];
      float n0 = (yy0 >= 0 && yy0 < HH && xx0 >= 0 && xx0 < WW)
                   ? gmS[(r + dy0[pr]) * 64 + (tx + dx0[pr])] : 0.0f;
      float n1 = (yy1 >= 0 && yy1 < HH && xx1 >= 0 && xx1 < WW)
                   ? gmS[(r + dy1[pr]) * 64 + (tx + dx1[pr])] : 0.0f;
      bool mask = (g <= n0) || (g < n1);
      edges[(size_t)n * HW + y * WW + x] = (!mask && (g > 0.1f)) ? 1.0f : 0.0f;
    }
  }
}

extern "C" void kernel_launch(void* const* d_in, const int* in_sizes, int n_in,
                              void* d_out, int out_size, void* d_ws, size_t ws_size,
                              hipStream_t stream) {
  const float* img = (const float*)d_in[0];
  float* out = (float*)d_out;
  char* ws = (char*)d_ws;

  float* ssmax  = (float*)ws;                  // 4 B (region padded to 256 B)
  float* magbuf = (float*)(ws + 256);          // 16 MiB

  float* edges = out;             // (16,1,512,512)
  float* sobel = out + 4194304;   // (16,2,512,512): c0=sy, c1=sx

  hipMemsetAsync(ssmax, 0, 4, stream);         // 0x0 == 0.0f, valid lower bound
  k1_mag<<<dim3(4096), dim3(256), 0, stream>>>(img, magbuf, (unsigned int*)ssmax);
  k34_sobel_nms<<<dim3((WW + OTW - 1) / OTW, (HH + OTH - 1) / OTH, 16),
                  dim3(64, 4), 0, stream>>>(magbuf, ssmax, sobel, edges);
}

// Round 3
// 123.595 us; speedup vs baseline: 1.3168x; 1.3168x over previous
//
#include <hip/hip_runtime.h>
#include <math.h>

#define HH 512
#define WW 512
#define HW (HH*WW)   // 262144

// Fused sobel+NMS tile geometry: each block computes a 64x16 gm region
// (identical per-pixel math to the previous k3) and outputs the interior
// 62x14 pixels after NMS against the LDS-resident gm halo.
#define OTW 62
#define OTH 14

__device__ __forceinline__ int refl(int i) {
  if (i < 0) return -i;
  if (i >= HH) return 2*HH - 2 - i;
  return i;
}

__device__ __forceinline__ float sumsq3(float r, float g, float b) {
  return __fadd_rn(__fadd_rn(__fmul_rn(r,r), __fmul_rn(g,g)), __fmul_rn(b,b));
}

// K1: mag = sqrt(sumsq over 3 channels), stored for k34, + per-block partial
// max via a plain store (NO single-address atomics — round-2 post-mortem:
// 4096 atomicMax to one address serialized the kernel, 12us -> 54us).
// sqrtf is correctly rounded + monotone, so max_i sqrt(ss_i) == sqrt(max_i ss_i)
// BIT-EXACTLY -> mm unchanged vs the original two-kernel ss reduction.
__global__ __launch_bounds__(256) void k1_mag(const float* __restrict__ img,
                                              float* __restrict__ mag,
                                              float* __restrict__ partials) {
  int gid = blockIdx.x * 256 + threadIdx.x;   // 0 .. 1048575 (float4 granules)
  int n  = gid >> 16;                         // 65536 float4 per image plane
  int p4 = gid & 65535;
  const float* base = img + (size_t)n * 3 * HW;
  float4 r = ((const float4*)(base        ))[p4];
  float4 g = ((const float4*)(base +   HW ))[p4];
  float4 b = ((const float4*)(base + 2*HW ))[p4];
  float4 s;
  s.x = sqrtf(sumsq3(r.x, g.x, b.x));
  s.y = sqrtf(sumsq3(r.y, g.y, b.y));
  s.z = sqrtf(sumsq3(r.z, g.z, b.z));
  s.w = sqrtf(sumsq3(r.w, g.w, b.w));
  ((float4*)mag)[gid] = s;

  float m = fmaxf(fmaxf(s.x, s.y), fmaxf(s.z, s.w));
  #pragma unroll
  for (int off = 32; off > 0; off >>= 1)
    m = fmaxf(m, __shfl_down(m, off));
  __shared__ float sm[4];
  int lane = threadIdx.x & 63, wv = threadIdx.x >> 6;
  if (lane == 0) sm[wv] = m;
  __syncthreads();
  if (threadIdx.x == 0)
    partials[blockIdx.x] = fmaxf(fmaxf(sm[0], sm[1]), fmaxf(sm[2], sm[3]));
}

// K1b: reduce 4096 partials -> magmax (single block, no atomics)
__global__ __launch_bounds__(256) void k1b_reduce(const float* __restrict__ partials,
                                                  float* __restrict__ magmax) {
  float m = 0.0f;
  #pragma unroll
  for (int i = 0; i < 16; ++i)
    m = fmaxf(m, partials[threadIdx.x + 256 * i]);
  #pragma unroll
  for (int off = 32; off > 0; off >>= 1)
    m = fmaxf(m, __shfl_down(m, off));
  __shared__ float sm[4];
  int lane = threadIdx.x & 63, wv = threadIdx.x >> 6;
  if (lane == 0) sm[wv] = m;
  __syncthreads();
  if (threadIdx.x == 0)
    magmax[0] = fmaxf(fmaxf(sm[0], sm[1]), fmaxf(sm[2], sm[3]));
}

// K34: normalize + 5x5 Sobel + grad_mag + phase + NMS + threshold, fused.
// gm region per block: 64 cols x 16 rows at image offset (oy0-1, ox0-1);
// outputs = interior 62x14. Per-pixel math is expression-identical to the
// previous rounds (same f64 row-aggregate factorization, same f32 rounding
// points, same zero-pad NMS semantics) -> bit-stable decisions.
__global__ __launch_bounds__(256) void k34_sobel_nms(const float* __restrict__ mag,
                                                     const float* __restrict__ magmax,
                                                     float* __restrict__ sobel_out,
                                                     float* __restrict__ edges) {
  __shared__ float magS[20 * 68];  // mag rows [oy0-3, oy0+17), cols [ox0-3, ox0+65)
  __shared__ float gmS[16 * 64];   // gm region
  int tx = threadIdx.x;            // 0..63 -> gm col
  int ty = threadIdx.y;            // 0..3
  int ox0 = blockIdx.x * OTW;      // first output col
  int oy0 = blockIdx.y * OTH;      // first output row
  int n  = blockIdx.z;
  const float* sp = mag + (size_t)n * HW;
  float mm = magmax[0];            // == sqrtf(max ss), bit-identical to before

  int tid = ty * 64 + tx;
  for (int i = tid; i < 20 * 68; i += 256) {
    int r = i / 68, c = i - r * 68;
    int gy = refl(oy0 - 3 + r);
    int gx = refl(ox0 - 3 + c);
    magS[i] = __fdiv_rn(sp[gy * WW + gx], mm);   // bit-identical to prior rounds
  }
  __syncthreads();

  // exact f32 weights (numpy-folded), widened to f64 exactly
  const double wA0 = (double)(-2.0f/8.0f/6.0f);
  const double wA1 = (double)(-2.0f/5.0f/6.0f);
  const double wA2 = (double)(-2.0f/1.0f/6.0f);
  const double wB0 = (double)(-1.0f/5.0f/6.0f);
  const double wB1 = (double)(-1.0f/2.0f/6.0f);
  const double wB2 = (double)(-1.0f/1.0f/6.0f);

  // per-row aggregates over the thread's 8-row window (tile rows 4ty..4ty+7)
  double S[8], T[8], C[8], D0[8], D1[8];
  #pragma unroll
  for (int j = 0; j < 8; ++j) {
    const float* rowp = &magS[(4 * ty + j) * 68 + tx];
    double v0 = (double)rowp[0], v1 = (double)rowp[1], v2 = (double)rowp[2],
           v3 = (double)rowp[3], v4 = (double)rowp[4];
    S[j]  = v0 + v4;  T[j]  = v1 + v3;  C[j] = v2;
    D0[j] = v0 - v4;  D1[j] = v1 - v3;
  }

  int x = ox0 - 1 + tx;            // image col of this thread's gm column
  bool xin = (tx >= 1) && (tx <= OTW) && (x < WW);
  int prpack = 0;                  // 2 bits per dy
  #pragma unroll
  for (int dy = 0; dy < 4; ++dy) {
    int r = 4 * ty + dy;           // gm-region row, 0..15
    int y = oy0 - 1 + r;           // image row
    int j = dy;                    // window base in aggregate arrays
    double asy = wA0*(S[j]-S[j+4]) + wA1*(T[j]-T[j+4]) + wA2*(C[j]-C[j+4])
               + wB0*(S[j+1]-S[j+3]) + wB1*(T[j+1]-T[j+3]) + wB2*(C[j+1]-C[j+3]);
    double asx = wA0*(D0[j]+D0[j+4]) + wA1*(D0[j+1]+D0[j+3]) + wA2*D0[j+2]
               + wB0*(D1[j]+D1[j+4]) + wB1*(D1[j+1]+D1[j+3]) + wB2*D1[j+2];
    float fsy = (float)asy, fsx = (float)asx;
    float g = sqrtf(__fadd_rn(__fmul_rn(fsx, fsx), __fmul_rn(fsy, fsy)));
    gmS[r * 64 + tx] = g;
    float ph = atan2f(fsx, __fadd_rn(fsy, 1e-5f));
    float pf = __fdiv_rn(ph, 0.78539816339744830962f);  // f32(pi/4)
    float rr = rintf(pf);                                // half-to-even like jnp.round
    int ip = ((int)rr + 4) & 7;                          // mod 8
    prpack |= (ip & 3) << (2 * dy);                      // SEL_IDS has period 4
    // sobel store for interior pixels
    if (xin && r >= 1 && r <= OTH && y < HH) {
      int p = y * WW + x;
      sobel_out[(size_t)n * 2 * HW + p]      = fsy;  // channel 0: sobel_y
      sobel_out[(size_t)n * 2 * HW + HW + p] = fsx;  // channel 1: sobel_x
    }
  }
  __syncthreads();

  // NMS + threshold on interior pixels, neighbors from LDS (zero-pad at image border)
  if (xin) {
    const int dy0[4] = {-1, -1,  0, -1};
    const int dx0[4] = { 0, -1, -1,  1};
    const int dy1[4] = { 1,  1,  0,  1};
    const int dx1[4] = { 0,  1,  1, -1};
    #pragma unroll
    for (int dy = 0; dy < 4; ++dy) {
      int r = 4 * ty + dy;
      if (r < 1 || r > OTH) continue;      // wave-uniform branch
      int y = oy0 - 1 + r;
      if (y >= HH) continue;
      int pr = (prpack >> (2 * dy)) & 3;
      float g = gmS[r * 64 + tx];
      int yy0 = y + dy0[pr], xx0 = x + dx0[pr];
      int yy1 = y + dy1[pr], xx1 = x + dx1[pr];
      float n0 = (yy0 >= 0 && yy0 < HH && xx0 >= 0 && xx0 < WW)
                   ? gmS[(r + dy0[pr]) * 64 + (tx + dx0[pr])] : 0.0f;
      float n1 = (yy1 >= 0 && yy1 < HH && xx1 >= 0 && xx1 < WW)
                   ? gmS[(r + dy1[pr]) * 64 + (tx + dx1[pr])] : 0.0f;
      bool mask = (g <= n0) || (g < n1);
      edges[(size_t)n * HW + y * WW + x] = (!mask && (g > 0.1f)) ? 1.0f : 0.0f;
    }
  }
}

extern "C" void kernel_launch(void* const* d_in, const int* in_sizes, int n_in,
                              void* d_out, int out_size, void* d_ws, size_t ws_size,
                              hipStream_t stream) {
  const float* img = (const float*)d_in[0];
  float* out = (float*)d_out;
  char* ws = (char*)d_ws;

  float* magmax   = (float*)ws;                 // 4 B (region padded to 256 B)
  float* partials = (float*)(ws + 256);         // 4096 floats = 16 KiB
  float* magbuf   = (float*)(ws + 256 + 16384); // 16 MiB

  float* edges = out;             // (16,1,512,512)
  float* sobel = out + 4194304;   // (16,2,512,512): c0=sy, c1=sx

  k1_mag   <<<dim3(4096), dim3(256), 0, stream>>>(img, magbuf, partials);
  k1b_reduce<<<dim3(1),   dim3(256), 0, stream>>>(partials, magmax);
  k34_sobel_nms<<<dim3((WW + OTW - 1) / OTW, (HH + OTH - 1) / OTH, 16),
                  dim3(64, 4), 0, stream>>>(magbuf, magmax, sobel, edges);
}